// Round 1
// baseline (362.014 us; speedup 1.0000x reference)
//
#include <hip/hip_runtime.h>
#include <cstdint>

#define P_BOX 8732
#define BATCH 32
#define NCLS 21
#define TOPK 200
// key encoding of masked score -1.0f: bits(−1.0)=0xBF800000, sign set -> ~bits
#define KEY_NEG1 0x407FFFFFu

__device__ __forceinline__ unsigned long long umax64(unsigned long long a, unsigned long long b) {
  return a > b ? a : b;
}

// monotonic float->u32 (total order), invertible
__device__ __forceinline__ uint32_t score_key(float m) {
  uint32_t b = __float_as_uint(m);
  return (b & 0x80000000u) ? ~b : (b | 0x80000000u);
}
__device__ __forceinline__ float key_score(uint32_t k) {
  uint32_t b = (k & 0x80000000u) ? (k ^ 0x80000000u) : ~k;
  return __uint_as_float(b);
}

// 64-bit shuffle helpers built on 32-bit shuffles (wave64)
__device__ __forceinline__ unsigned long long shfl_down_u64(unsigned long long v, int off) {
  int lo = (int)(uint32_t)(v & 0xFFFFFFFFull);
  int hi = (int)(uint32_t)(v >> 32);
  lo = __shfl_down(lo, off, 64);
  hi = __shfl_down(hi, off, 64);
  return ((unsigned long long)(uint32_t)hi << 32) | (uint32_t)lo;
}
__device__ __forceinline__ unsigned long long shfl_u64(unsigned long long v, int lane) {
  int lo = (int)(uint32_t)(v & 0xFFFFFFFFull);
  int hi = (int)(uint32_t)(v >> 32);
  lo = __shfl(lo, lane, 64);
  hi = __shfl(hi, lane, 64);
  return ((unsigned long long)(uint32_t)hi << 32) | (uint32_t)lo;
}

// Exactly mirrors reference _decode (fp32): priors clipped to >=1e-6, var=(0.1,0.2),
// log-wh clamped to [-4,4], corners clamped to [0,1].
__device__ __forceinline__ float4 decode_box(const float4 pr, const float4 lc) {
  float px = fmaxf(pr.x, 1e-6f), py = fmaxf(pr.y, 1e-6f);
  float pw = fmaxf(pr.z, 1e-6f), ph = fmaxf(pr.w, 1e-6f);
  float cx = px + lc.x * 0.1f * pw;
  float cy = py + lc.y * 0.1f * ph;
  float lw = fminf(fmaxf(lc.z * 0.2f, -4.0f), 4.0f);
  float lh = fminf(fmaxf(lc.w * 0.2f, -4.0f), 4.0f);
  float w = pw * expf(lw);
  float h = ph * expf(lh);
  float4 r;
  r.x = fminf(fmaxf(cx - 0.5f * w, 0.0f), 1.0f);
  r.y = fminf(fmaxf(cy - 0.5f * h, 0.0f), 1.0f);
  r.z = fminf(fmaxf(cx + 0.5f * w, 0.0f), 1.0f);
  r.w = fminf(fmaxf(cy + 0.5f * h, 0.0f), 1.0f);
  return r;
}

// Kernel 1: per-box softmax (all 21 classes, class-major store) + box decode.
__global__ __launch_bounds__(256) void prep_kernel(
    const float* __restrict__ loc, const float* __restrict__ conf,
    const float* __restrict__ priors, float* __restrict__ probsT,
    float4* __restrict__ boxes) {
  int idx = blockIdx.x * 256 + threadIdx.x;
  if (idx >= BATCH * P_BOX) return;
  int b = idx / P_BOX, p = idx - b * P_BOX;
  const float* cf = conf + (size_t)idx * NCLS;
  float x[NCLS];
  float mx = -1e30f;
#pragma unroll
  for (int i = 0; i < NCLS; ++i) {
    float v = fminf(fmaxf(cf[i], -100.0f), 100.0f);
    x[i] = v;
    mx = fmaxf(mx, v);
  }
  float s = 0.0f;
#pragma unroll
  for (int i = 0; i < NCLS; ++i) {
    x[i] = expf(x[i] - mx);
    s += x[i];
  }
  float inv = 1.0f / s;
  float* pt = probsT + (size_t)b * NCLS * P_BOX + p;
#pragma unroll
  for (int i = 0; i < NCLS; ++i) pt[(size_t)i * P_BOX] = x[i] * inv;
  float4 pr = ((const float4*)priors)[p];
  float4 lc = ((const float4*)loc)[idx];
  boxes[idx] = decode_box(pr, lc);
}

// Kernel 2: one block per (b,c) task. Top-200 tournament select + greedy NMS + compact.
template <bool USE_WS>
__global__ __launch_bounds__(256) void nms_kernel(
    const float* __restrict__ loc, const float* __restrict__ conf,
    const float* __restrict__ priors, const float* __restrict__ probsT,
    const float4* __restrict__ boxes, float* __restrict__ out) {
  const int t = threadIdx.x;
  const int task = blockIdx.x;  // b*21 + c
  const int b = task / NCLS, c = task - b * NCLS;
  float* ob = out + (size_t)task * TOPK * 5;

  if (c == 0) {  // background class: all-zero rows
    for (int i = t; i < TOPK * 5; i += 256) ob[i] = 0.0f;
    return;
  }

  __shared__ uint32_t s_key[P_BOX];                 // per-box masked-score key
  __shared__ unsigned long long s_red[2][4];        // cross-wave reduce (double-buffered)
  __shared__ unsigned long long s_sel[TOPK];        // winners (key<<32 | P-p)
  __shared__ float4 s_box[TOPK];
  __shared__ float s_score[TOPK];
  __shared__ float s_area[TOPK];
  __shared__ int s_alive[TOPK];
  __shared__ int s_kept[TOPK];
  __shared__ int s_nk;

  // ---- scan: compute keys, per-thread head (max over own strided slots) ----
  unsigned long long head = 0ull;
  for (int p = t; p < P_BOX; p += 256) {
    float sc;
    float4 bx;
    if (USE_WS) {
      sc = probsT[(size_t)(b * NCLS + c) * P_BOX + p];
      bx = boxes[(size_t)b * P_BOX + p];
    } else {
      const float* cf = conf + ((size_t)b * P_BOX + p) * NCLS;
      float x[NCLS];
      float mx = -1e30f;
#pragma unroll
      for (int i = 0; i < NCLS; ++i) {
        float v = fminf(fmaxf(cf[i], -100.0f), 100.0f);
        x[i] = v;
        mx = fmaxf(mx, v);
      }
      float ssum = 0.0f, e = 0.0f;
#pragma unroll
      for (int i = 0; i < NCLS; ++i) {
        float ex = expf(x[i] - mx);
        ssum += ex;
        if (i == c) e = ex;
      }
      sc = e / ssum;
      bx = decode_box(((const float4*)priors)[p], ((const float4*)loc)[(size_t)b * P_BOX + p]);
    }
    bool valid = (sc > 0.01f) && (bx.z > bx.x + 1e-6f) && (bx.w > bx.y + 1e-6f);
    float m = valid ? sc : -1.0f;
    uint32_t k = score_key(m);
    s_key[p] = k;
    unsigned long long pk = ((unsigned long long)k << 32) | (uint32_t)(P_BOX - p);
    head = umax64(head, pk);  // ties -> larger (P-p) -> smaller p, matches top_k
  }

  // ---- 200 rounds of tournament selection (1 barrier per round) ----
  int nsel = TOPK;
  for (int r = 0; r < TOPK; ++r) {
    unsigned long long v = head;
#pragma unroll
    for (int off = 32; off > 0; off >>= 1) v = umax64(v, shfl_down_u64(v, off));
    if ((t & 63) == 0) s_red[r & 1][t >> 6] = v;
    __syncthreads();
    unsigned long long w = umax64(umax64(s_red[r & 1][0], s_red[r & 1][1]),
                                  umax64(s_red[r & 1][2], s_red[r & 1][3]));
    uint32_t wkey = (uint32_t)(w >> 32);
    if (wkey <= KEY_NEG1) {  // winner is masked(-1) or consumed: nothing valid left
      nsel = r;
      break;
    }
    if (t == 0) s_sel[r] = w;
    int p = P_BOX - (int)(w & 0xFFFFFFFFull);
    int owner = p & 255;
    if ((t >> 6) == (owner >> 6)) {  // winner-owner's wave cooperatively rescans
      int l = t & 63;
      int q = owner + (l << 8);
      unsigned long long pk = 0ull;
      if (q < P_BOX && q != p)
        pk = ((unsigned long long)s_key[q] << 32) | (uint32_t)(P_BOX - q);
#pragma unroll
      for (int off = 32; off > 0; off >>= 1) pk = umax64(pk, shfl_down_u64(pk, off));
      pk = shfl_u64(pk, 0);
      if (t == owner) {
        head = pk;
        s_key[p] = 0u;  // consume (0 < any real key incl. masked -1)
      }
    }
  }
  __syncthreads();

  // ---- gather top-nsel boxes/scores ----
  if (t < nsel) {
    unsigned long long w = s_sel[t];
    uint32_t k = (uint32_t)(w >> 32);
    int p = P_BOX - (int)(w & 0xFFFFFFFFull);
    float sc = key_score(k);
    float4 bx;
    if (USE_WS)
      bx = boxes[(size_t)b * P_BOX + p];
    else
      bx = decode_box(((const float4*)priors)[p], ((const float4*)loc)[(size_t)b * P_BOX + p]);
    s_score[t] = sc;
    s_box[t] = bx;
    s_area[t] = (bx.z - bx.x) * (bx.w - bx.y);
    s_alive[t] = 1;
  }
  __syncthreads();

  // ---- greedy NMS, exact fori_loop semantics (dead boxes don't suppress) ----
  for (int i = 0; i < nsel; ++i) {
    if (s_alive[i]) {  // uniform read
      if (t > i && t < nsel && s_alive[t]) {
        float4 bi = s_box[i];
        float4 bj = s_box[t];
        float lx = fmaxf(bi.x, bj.x), ly = fmaxf(bi.y, bj.y);
        float rx = fminf(bi.z, bj.z), ry = fminf(bi.w, bj.w);
        float iw = fmaxf(rx - lx, 0.0f), ih = fmaxf(ry - ly, 0.0f);
        float inter = iw * ih;
        float uni = s_area[i] + s_area[t] - inter;
        float iou = inter / fmaxf(uni, 1e-12f);
        if (iou > 0.45f) s_alive[t] = 0;
      }
      __syncthreads();
    }
  }

  // ---- compact kept to front (score order preserved), zero-fill rest ----
  if (t == 0) {
    int cnt = 0;
    for (int i = 0; i < nsel; ++i)
      if (s_alive[i]) s_kept[cnt++] = i;
    s_nk = cnt;
  }
  __syncthreads();
  int nk = s_nk;
  if (t < TOPK) {
    float r0 = 0.f, r1 = 0.f, r2 = 0.f, r3 = 0.f, r4 = 0.f;
    if (t < nk) {
      int j = s_kept[t];
      r0 = s_score[j];
      float4 bx = s_box[j];
      r1 = bx.x;
      r2 = bx.y;
      r3 = bx.z;
      r4 = bx.w;
    }
    float* o = ob + t * 5;
    o[0] = r0;
    o[1] = r1;
    o[2] = r2;
    o[3] = r3;
    o[4] = r4;
  }
}

extern "C" void kernel_launch(void* const* d_in, const int* in_sizes, int n_in,
                              void* d_out, int out_size, void* d_ws, size_t ws_size,
                              hipStream_t stream) {
  (void)in_sizes;
  (void)n_in;
  (void)out_size;
  const float* loc = (const float*)d_in[0];     // [B,P,4]
  const float* conf = (const float*)d_in[1];    // [B,P,21]
  const float* priors = (const float*)d_in[2];  // [P,4]
  float* out = (float*)d_out;                   // [B,21,200,5]

  size_t probs_bytes = (size_t)BATCH * NCLS * P_BOX * sizeof(float);
  size_t boxes_bytes = (size_t)BATCH * P_BOX * sizeof(float4);
  if (ws_size >= probs_bytes + boxes_bytes) {
    float* probsT = (float*)d_ws;
    float4* boxes = (float4*)((char*)d_ws + probs_bytes);
    int nprep = BATCH * P_BOX;
    prep_kernel<<<(nprep + 255) / 256, 256, 0, stream>>>(loc, conf, priors, probsT, boxes);
    nms_kernel<true><<<BATCH * NCLS, 256, 0, stream>>>(loc, conf, priors, probsT, boxes, out);
  } else {
    nms_kernel<false><<<BATCH * NCLS, 256, 0, stream>>>(loc, conf, priors, nullptr, nullptr, out);
  }
}

// Round 2
// 192.476 us; speedup vs baseline: 1.8808x; 1.8808x over previous
//
#include <hip/hip_runtime.h>
#include <cstdint>

#define P_BOX 8732
#define BATCH 32
#define NCLS 21
#define TOPK 200
#define NCHUNK 9      // ceil(8732/1024); chunk 8 partial (t < 135 only)
#define CAND_CAP 512

typedef unsigned long long u64;

// monotonic float->u32 (total order), invertible
__device__ __forceinline__ uint32_t score_key(float m) {
  uint32_t b = __float_as_uint(m);
  return (b & 0x80000000u) ? ~b : (b | 0x80000000u);
}
__device__ __forceinline__ float key_score(uint32_t k) {
  uint32_t b = (k & 0x80000000u) ? (k ^ 0x80000000u) : ~k;
  return __uint_as_float(b);
}

// Exactly mirrors reference _decode (fp32).
__device__ __forceinline__ float4 decode_box(const float4 pr, const float4 lc) {
  float px = fmaxf(pr.x, 1e-6f), py = fmaxf(pr.y, 1e-6f);
  float pw = fmaxf(pr.z, 1e-6f), ph = fmaxf(pr.w, 1e-6f);
  float cx = px + lc.x * 0.1f * pw;
  float cy = py + lc.y * 0.1f * ph;
  float lw = fminf(fmaxf(lc.z * 0.2f, -4.0f), 4.0f);
  float lh = fminf(fmaxf(lc.w * 0.2f, -4.0f), 4.0f);
  float w = pw * expf(lw);
  float h = ph * expf(lh);
  float4 r;
  r.x = fminf(fmaxf(cx - 0.5f * w, 0.0f), 1.0f);
  r.y = fminf(fmaxf(cy - 0.5f * h, 0.0f), 1.0f);
  r.z = fminf(fmaxf(cx + 0.5f * w, 0.0f), 1.0f);
  r.w = fminf(fmaxf(cy + 0.5f * h, 0.0f), 1.0f);
  return r;
}

// Prep: per (b,p) thread computes softmax (division, like jax), decode,
// validity, and stores masked score-keys for classes 1..20.
// Layout: keys[(b*20 + (c-1))*P_BOX + p] — per-class coalesced.
__global__ __launch_bounds__(256) void prep_kernel(
    const float* __restrict__ loc, const float* __restrict__ conf,
    const float* __restrict__ priors, uint32_t* __restrict__ keys) {
  int idx = blockIdx.x * 256 + threadIdx.x;
  if (idx >= BATCH * P_BOX) return;
  int b = idx / P_BOX, p = idx - b * P_BOX;
  const float* cf = conf + (size_t)idx * NCLS;
  float x[NCLS];
  float mx = -1e30f;
#pragma unroll
  for (int i = 0; i < NCLS; ++i) {
    float v = fminf(fmaxf(cf[i], -100.0f), 100.0f);
    x[i] = v;
    mx = fmaxf(mx, v);
  }
  float s = 0.0f;
#pragma unroll
  for (int i = 0; i < NCLS; ++i) {
    x[i] = expf(x[i] - mx);
    s += x[i];
  }
  float4 bx = decode_box(((const float4*)priors)[p], ((const float4*)loc)[idx]);
  bool bok = (bx.z > bx.x + 1e-6f) && (bx.w > bx.y + 1e-6f);
#pragma unroll
  for (int ci = 1; ci < NCLS; ++ci) {
    float sc = x[ci] / s;  // division, matching reference softmax
    float m = (bok && sc > 0.01f) ? sc : -1.0f;
    keys[((size_t)(b * 20) + (ci - 1)) * P_BOX + p] = score_key(m);
  }
}

__device__ __forceinline__ int cnt_ge_key(const uint32_t* kv, uint32_t T) {
  int n = 0;
#pragma unroll
  for (int i = 0; i < NCHUNK * 4; ++i) n += (kv[i] >= T) ? 1 : 0;
  return n;
}
__device__ __forceinline__ int cnt_eq_idx(const uint32_t* kv, int t, uint32_t T, uint32_t I) {
  int n = 0;
#pragma unroll
  for (int ch = 0; ch < NCHUNK; ++ch) {
#pragma unroll
    for (int e = 0; e < 4; ++e) {
      int p = ch * 1024 + t * 4 + e;
      n += (kv[ch * 4 + e] == T && (uint32_t)(P_BOX - p) >= I) ? 1 : 0;
    }
  }
  return n;
}

// Block-wide sum with ONE barrier per call; 3-slot rotation avoids the
// zero-vs-read race (slot it%3 hot for adds in window it, reads in window
// it+1; zeroed in window it-1 via (it+1)%3 of the previous call).
__device__ __forceinline__ int block_count(int v, int t, int* s_cnt, int& it) {
#pragma unroll
  for (int o = 32; o > 0; o >>= 1) v += __shfl_down(v, o, 64);
  int slot = it % 3;
  if (t == 0) s_cnt[(it + 1) % 3] = 0;
  if ((t & 63) == 0) atomicAdd(&s_cnt[slot], v);
  __syncthreads();
  int r = s_cnt[slot];
  ++it;
  return r;
}

template <bool USE_WS>
__global__ __launch_bounds__(256) void nms_kernel(
    const float* __restrict__ loc, const float* __restrict__ conf,
    const float* __restrict__ priors, const uint32_t* __restrict__ keys,
    float* __restrict__ out) {
  const int t = threadIdx.x;
  const int task = blockIdx.x;  // b*21 + c
  const int b = task / NCLS, c = task - b * NCLS;
  float* ob = out + (size_t)task * TOPK * 5;

  if (c == 0) {  // background class: all-zero rows
    for (int i = t; i < TOPK * 5; i += 256) ob[i] = 0.0f;
    return;
  }

  __shared__ int s_cnt[3];
  __shared__ int s_m;
  __shared__ u64 s_cand[CAND_CAP];
  __shared__ u64 s_sel[TOPK];
  __shared__ float4 s_box[256];
  __shared__ float s_area[256];
  __shared__ float s_score[256];
  __shared__ u64 s_sup[TOPK * 4];
  __shared__ u64 s_alive[4];
  __shared__ short s_kept[TOPK];

  if (t == 0) {
    s_cnt[0] = 0; s_cnt[1] = 0; s_cnt[2] = 0;
    s_m = 0;
  }

  // ---- load/compute this (b,c)'s 8732 keys into registers (36/thread) ----
  // p(chunk,e) = chunk*1024 + 4*t + e; pad slots hold key 0 (< any threshold)
  uint32_t kv[NCHUNK * 4];
  if (USE_WS) {
    const uint4* kp = (const uint4*)(keys + (size_t)(b * 20 + (c - 1)) * P_BOX);
#pragma unroll
    for (int ch = 0; ch < 8; ++ch) {
      uint4 v = kp[ch * 256 + t];
      kv[ch * 4 + 0] = v.x; kv[ch * 4 + 1] = v.y;
      kv[ch * 4 + 2] = v.z; kv[ch * 4 + 3] = v.w;
    }
    if (t < 135) {
      uint4 v = kp[2048 + t];
      kv[32] = v.x; kv[33] = v.y; kv[34] = v.z; kv[35] = v.w;
    } else {
      kv[32] = 0u; kv[33] = 0u; kv[34] = 0u; kv[35] = 0u;
    }
  } else {
    for (int ch = 0; ch < NCHUNK; ++ch) {
      int p0 = ch * 1024 + 4 * t;
#pragma unroll
      for (int e = 0; e < 4; ++e) {
        int p = p0 + e;
        uint32_t k = 0u;
        if (p < P_BOX) {
          const float* cf = conf + (size_t)(b * P_BOX + p) * NCLS;
          float x[NCLS];
          float mx = -1e30f;
#pragma unroll
          for (int i = 0; i < NCLS; ++i) {
            float v = fminf(fmaxf(cf[i], -100.0f), 100.0f);
            x[i] = v;
            mx = fmaxf(mx, v);
          }
          float ssum = 0.0f, ec = 0.0f;
#pragma unroll
          for (int i = 0; i < NCLS; ++i) {
            float ex = expf(x[i] - mx);
            ssum += ex;
            if (i == c) ec = ex;
          }
          float sc = ec / ssum;
          float4 bx = decode_box(((const float4*)priors)[p],
                                 ((const float4*)loc)[(size_t)b * P_BOX + p]);
          bool valid = (sc > 0.01f) && (bx.z > bx.x + 1e-6f) && (bx.w > bx.y + 1e-6f);
          k = score_key(valid ? sc : -1.0f);
        }
        kv[ch * 4 + e] = k;
      }
    }
  }
  __syncthreads();  // init (s_cnt/s_m) visible before first block_count

  // ---- binary search for the 200th-largest key ----
  int it = 0;
  const uint32_t KLO = score_key(0.01f);  // eligible <=> key > KLO
  int V = block_count(cnt_ge_key(kv, KLO + 1), t, s_cnt, it);
  uint32_t T;
  bool two = false;
  uint32_t I = 1;
  if (V <= TOPK) {
    T = KLO + 1;  // take all eligible (M = V)
  } else {
    uint32_t lo = KLO + 1, hi = score_key(1.0f) + 1;  // f(lo)>=200, f(hi)=0
    while (hi - lo > 1) {
      uint32_t mid = lo + ((hi - lo) >> 1);
      int cnt = block_count(cnt_ge_key(kv, mid), t, s_cnt, it);
      if (cnt >= TOPK) lo = mid; else hi = mid;
    }
    T = lo;  // f(T) >= 200 > f(T+1)
    int M0 = block_count(cnt_ge_key(kv, T), t, s_cnt, it);
    if (M0 > CAND_CAP) {  // pathological tie block: refine on index
      int G = block_count(cnt_ge_key(kv, T + 1), t, s_cnt, it);
      int R = TOPK - G;  // >= 1
      uint32_t lo2 = 1, hi2 = P_BOX + 1;
      while (hi2 - lo2 > 1) {
        uint32_t mid = lo2 + ((hi2 - lo2) >> 1);
        int cnt = block_count(cnt_eq_idx(kv, t, T, mid), t, s_cnt, it);
        if (cnt >= R) lo2 = mid; else hi2 = mid;
      }
      I = lo2;  // exactly R equals qualify -> M = 200 exactly
      two = true;
    }
  }

  // ---- gather candidates >= threshold (packed key|P-p for exact ordering) ----
#pragma unroll
  for (int ch = 0; ch < NCHUNK; ++ch) {
#pragma unroll
    for (int e = 0; e < 4; ++e) {
      uint32_t k = kv[ch * 4 + e];
      int p = ch * 1024 + t * 4 + e;
      bool take = two ? (k >= T + 1 || (k == T && (uint32_t)(P_BOX - p) >= I))
                      : (k >= T);
      if (take) {
        int ix = atomicAdd(&s_m, 1);
        if (ix < CAND_CAP)
          s_cand[ix] = ((u64)k << 32) | (uint32_t)(P_BOX - p);
      }
    }
  }
  __syncthreads();
  int M = min(s_m, CAND_CAP);
  int nsel = min(M, TOPK);

  // ---- rank (exact total order; ties by smaller p) and scatter sorted ----
  for (int ci = t; ci < M; ci += 256) {
    u64 mine = s_cand[ci];
    int r = 0;
    for (int j = 0; j < M; ++j) r += (s_cand[j] > mine) ? 1 : 0;  // LDS broadcast
    if (r < TOPK) s_sel[r] = mine;
  }
  __syncthreads();

  // ---- decode selected boxes ----
  if (t < nsel) {
    u64 w = s_sel[t];
    uint32_t k = (uint32_t)(w >> 32);
    int p = P_BOX - (int)(uint32_t)(w & 0xFFFFFFFFull);
    float4 bx = decode_box(((const float4*)priors)[p],
                           ((const float4*)loc)[(size_t)b * P_BOX + p]);
    s_box[t] = bx;
    s_area[t] = (bx.z - bx.x) * (bx.w - bx.y);
    s_score[t] = key_score(k);
  } else {
    s_box[t] = make_float4(0.f, 0.f, 0.f, 0.f);
    s_area[t] = 0.f;
    s_score[t] = 0.f;
  }
  for (int i = t; i < TOPK * 4; i += 256) s_sup[i] = 0ull;
  __syncthreads();

  // ---- suppression bitmasks: row i word c = ballot(iou(i, c*64+l) > 0.45, j>i) ----
  {
    int wv = t >> 6, l = t & 63;
    float4 bj[4];
    float aj[4];
#pragma unroll
    for (int cc = 0; cc < 4; ++cc) {
      int j = cc * 64 + l;
      bj[cc] = s_box[j];
      aj[cc] = s_area[j];
    }
    for (int i = wv; i < nsel; i += 4) {  // wave-strided rows; per-wave uniform
      float4 bi = s_box[i];
      float ai = s_area[i];
      int c0 = i >> 6;  // triangular: only chunks containing j > i
      for (int cc = c0; cc < 4; ++cc) {
        int j = cc * 64 + l;
        float lx = fmaxf(bi.x, bj[cc].x), ly = fmaxf(bi.y, bj[cc].y);
        float rx = fminf(bi.z, bj[cc].z), ry = fminf(bi.w, bj[cc].w);
        float iw = fmaxf(rx - lx, 0.0f), ih = fmaxf(ry - ly, 0.0f);
        float inter = iw * ih;
        float uni = ai + aj[cc] - inter;
        float iou = inter / fmaxf(uni, 1e-12f);
        bool sup = (j > i) && (j < nsel) && (iou > 0.45f);
        u64 m = __ballot(sup);
        if (l == 0) s_sup[i * 4 + cc] = m;
      }
    }
  }
  __syncthreads();

  // ---- serial greedy walk over bitmasks (exact fori_loop semantics) ----
  if (t == 0) {
    u64 aw[4];
#pragma unroll
    for (int k2 = 0; k2 < 4; ++k2) {
      int rem = nsel - 64 * k2;
      aw[k2] = rem >= 64 ? ~0ull : (rem <= 0 ? 0ull : ((1ull << rem) - 1ull));
    }
    for (int i = 0; i < nsel; ++i) {
      if ((aw[i >> 6] >> (i & 63)) & 1ull) {
        aw[0] &= ~s_sup[i * 4 + 0];
        aw[1] &= ~s_sup[i * 4 + 1];
        aw[2] &= ~s_sup[i * 4 + 2];
        aw[3] &= ~s_sup[i * 4 + 3];
      }
    }
    s_alive[0] = aw[0]; s_alive[1] = aw[1];
    s_alive[2] = aw[2]; s_alive[3] = aw[3];
  }
  __syncthreads();

  // ---- compact kept to front via popcount ranks ----
  u64 w0 = s_alive[0], w1 = s_alive[1], w2 = s_alive[2], w3 = s_alive[3];
  int pc0 = __popcll(w0), pc01 = pc0 + __popcll(w1), pc012 = pc01 + __popcll(w2);
  int nk = pc012 + __popcll(w3);
  if (t < nsel) {
    int word = t >> 6, bit = t & 63;
    u64 wt = (word == 0) ? w0 : (word == 1) ? w1 : (word == 2) ? w2 : w3;
    if ((wt >> bit) & 1ull) {
      int base = (word == 0) ? 0 : (word == 1) ? pc0 : (word == 2) ? pc01 : pc012;
      int r = base + __popcll(wt & ((1ull << bit) - 1ull));
      s_kept[r] = (short)t;
    }
  }
  __syncthreads();

  // ---- write rows: [score, x1, y1, x2, y2], zeros past nk ----
  if (t < TOPK) {
    float r0 = 0.f, r1 = 0.f, r2 = 0.f, r3 = 0.f, r4 = 0.f;
    if (t < nk) {
      int j = s_kept[t];
      r0 = s_score[j];
      float4 bx = s_box[j];
      r1 = bx.x; r2 = bx.y; r3 = bx.z; r4 = bx.w;
    }
    float* o = ob + t * 5;
    o[0] = r0; o[1] = r1; o[2] = r2; o[3] = r3; o[4] = r4;
  }
}

extern "C" void kernel_launch(void* const* d_in, const int* in_sizes, int n_in,
                              void* d_out, int out_size, void* d_ws, size_t ws_size,
                              hipStream_t stream) {
  (void)in_sizes;
  (void)n_in;
  (void)out_size;
  const float* loc = (const float*)d_in[0];     // [B,P,4]
  const float* conf = (const float*)d_in[1];    // [B,P,21]
  const float* priors = (const float*)d_in[2];  // [P,4]
  float* out = (float*)d_out;                   // [B,21,200,5]

  size_t keys_bytes = (size_t)BATCH * 20 * P_BOX * sizeof(uint32_t);  // 22.35 MB
  if (ws_size >= keys_bytes) {
    uint32_t* keys = (uint32_t*)d_ws;
    int nprep = BATCH * P_BOX;
    prep_kernel<<<(nprep + 255) / 256, 256, 0, stream>>>(loc, conf, priors, keys);
    nms_kernel<true><<<BATCH * NCLS, 256, 0, stream>>>(loc, conf, priors, keys, out);
  } else {
    nms_kernel<false><<<BATCH * NCLS, 256, 0, stream>>>(loc, conf, priors, nullptr, out);
  }
}

// Round 3
// 185.101 us; speedup vs baseline: 1.9558x; 1.0398x over previous
//
#include <hip/hip_runtime.h>
#include <cstdint>

#define P_BOX 8732
#define NBOX_TOTAL 279424  // 32*8732
#define BATCH 32
#define NCLS 21
#define TOPK 200
#define NTH 512
#define NCH 5  // chunks of 2048 boxes; chunk 4 partial (t < 135)
#define CAND_CAP 1024
#define NORM 0xBC23D70Bu  // score_key(0.01f)+1 ; stored keys are pre-normalized
#define LIM (1u << 26)    // normalized key < LIM  <=>  eligible (score > 0.01)
#define CONF_F4 1466976   // 32*8732*21/4

typedef unsigned long long u64;

// monotonic float->u32 (total order), invertible
__device__ __forceinline__ uint32_t score_key(float m) {
  uint32_t b = __float_as_uint(m);
  return (b & 0x80000000u) ? ~b : (b | 0x80000000u);
}
__device__ __forceinline__ float key_score(uint32_t k) {
  uint32_t b = (k & 0x80000000u) ? (k ^ 0x80000000u) : ~k;
  return __uint_as_float(b);
}

// Exactly mirrors reference _decode (fp32).
__device__ __forceinline__ float4 decode_box(const float4 pr, const float4 lc) {
  float px = fmaxf(pr.x, 1e-6f), py = fmaxf(pr.y, 1e-6f);
  float pw = fmaxf(pr.z, 1e-6f), ph = fmaxf(pr.w, 1e-6f);
  float cx = px + lc.x * 0.1f * pw;
  float cy = py + lc.y * 0.1f * ph;
  float lw = fminf(fmaxf(lc.z * 0.2f, -4.0f), 4.0f);
  float lh = fminf(fmaxf(lc.w * 0.2f, -4.0f), 4.0f);
  float w = pw * expf(lw);
  float h = ph * expf(lh);
  float4 r;
  r.x = fminf(fmaxf(cx - 0.5f * w, 0.0f), 1.0f);
  r.y = fminf(fmaxf(cy - 0.5f * h, 0.0f), 1.0f);
  r.z = fminf(fmaxf(cx + 0.5f * w, 0.0f), 1.0f);
  r.w = fminf(fmaxf(cy + 0.5f * h, 0.0f), 1.0f);
  return r;
}

// Prep: 256 boxes/block. Stage conf in LDS (coalesced float4 global loads;
// stride-21 LDS reads are conflict-free since 21 is odd). Emit normalized
// masked score-keys, class-major: keys[(b*20 + c-1)*P_BOX + p].
__global__ __launch_bounds__(256) void prep_kernel(
    const float* __restrict__ loc, const float* __restrict__ conf,
    const float* __restrict__ priors, uint32_t* __restrict__ keys) {
  __shared__ float s_conf[256 * 21];  // 21504 B
  const int t = threadIdx.x;
  const int blk = blockIdx.x;
  const float4* cf4 = (const float4*)conf;
  size_t base4 = (size_t)blk * 1344;
#pragma unroll
  for (int i = t; i < 1344; i += 256) {
    size_t g4 = base4 + i;
    if (g4 < CONF_F4) ((float4*)s_conf)[i] = cf4[g4];
  }
  __syncthreads();
  int g = blk * 256 + t;
  if (g >= NBOX_TOTAL) return;
  int b = g / P_BOX, p = g - b * P_BOX;
  float x[NCLS];
  float mx = -1e30f;
#pragma unroll
  for (int i = 0; i < NCLS; ++i) {
    float v = fminf(fmaxf(s_conf[t * 21 + i], -100.0f), 100.0f);
    x[i] = v;
    mx = fmaxf(mx, v);
  }
  float s = 0.0f;
#pragma unroll
  for (int i = 0; i < NCLS; ++i) {
    x[i] = expf(x[i] - mx);
    s += x[i];
  }
  float4 bx = decode_box(((const float4*)priors)[p], ((const float4*)loc)[g]);
  bool bok = (bx.z > bx.x + 1e-6f) && (bx.w > bx.y + 1e-6f);
#pragma unroll
  for (int ci = 1; ci < NCLS; ++ci) {
    float sc = x[ci] / s;  // division, matching reference softmax
    float m = (bok && sc > 0.01f) ? sc : -1.0f;
    keys[((size_t)(b * 20) + (ci - 1)) * P_BOX + p] = score_key(m) - NORM;
  }
}

__device__ __forceinline__ int cnt_ge(const uint32_t* kv, uint32_t X) {
  int n = 0;
#pragma unroll
  for (int j = 0; j < NCH * 4; ++j) n += (kv[j] >= X && kv[j] < LIM) ? 1 : 0;
  return n;
}
__device__ __forceinline__ int cnt_eq_idx(const uint32_t* kv, int t, uint32_t T, uint32_t I) {
  int n = 0;
#pragma unroll
  for (int ch = 0; ch < NCH; ++ch) {
#pragma unroll
    for (int e = 0; e < 4; ++e) {
      int p = ch * 2048 + t * 4 + e;
      n += (kv[ch * 4 + e] == T && (uint32_t)(P_BOX - p) >= I) ? 1 : 0;
    }
  }
  return n;
}

// Block-wide sum, ONE barrier per call (3-slot rotation; slot it%3 accumulates
// in window it, is read after its barrier, and was zeroed in the previous call).
__device__ __forceinline__ int block_count(int v, int t, int* s_cnt, int& it) {
#pragma unroll
  for (int o = 32; o > 0; o >>= 1) v += __shfl_down(v, o, 64);
  int slot = it % 3;
  if (t == 0) s_cnt[(it + 1) % 3] = 0;
  if ((t & 63) == 0) atomicAdd(&s_cnt[slot], v);
  __syncthreads();
  int r = s_cnt[slot];
  ++it;
  return r;
}

// Find largest bucket B (of 4096) with suffix-count >= need; returns
// {B, M=suffix(B), above=suffix(B+1)}. If total < need: {0, total, 0}.
__device__ __forceinline__ int3 select_bucket(const int* s_hist, int* s_S,
                                              int* s_wt, int* s_res, int need,
                                              int t) {
  int base = t * 8;
  int ps = 0;
#pragma unroll
  for (int i = 0; i < 8; ++i) ps += s_hist[base + i];
  int l = t & 63, w = t >> 6;
  int v = ps;
#pragma unroll
  for (int off = 1; off < 64; off <<= 1) {
    int o = __shfl_down(v, off, 64);
    v += (l + off < 64) ? o : 0;  // inclusive suffix scan within wave
  }
  if (l == 0) s_wt[w] = v;
  __syncthreads();
  int hi = 0;
#pragma unroll
  for (int w2 = 0; w2 < 8; ++w2) hi += (w2 > w) ? s_wt[w2] : 0;
  int S = v + hi;  // suffix-count from bucket base = t*8
  s_S[t] = S;
  __syncthreads();
  if (t == 0 && s_S[0] < need) {
    s_res[0] = 0; s_res[1] = s_S[0]; s_res[2] = 0;
  } else if (s_S[t] >= need && (t == NTH - 1 || s_S[t + 1] < need)) {
    int suf = (t == NTH - 1) ? 0 : s_S[t + 1];
    int B = base, M = 0;
    for (int j = base + 7; j >= base; --j) {
      suf += s_hist[j];
      if (suf >= need) { B = j; M = suf; break; }
    }
    s_res[0] = B; s_res[1] = M; s_res[2] = M - s_hist[B];
  }
  __syncthreads();
  return make_int3(s_res[0], s_res[1], s_res[2]);
}

template <bool USE_WS>
__global__ __launch_bounds__(512) void nms_kernel(
    const float* __restrict__ loc, const float* __restrict__ conf,
    const float* __restrict__ priors, const uint32_t* __restrict__ keys,
    float* __restrict__ out) {
  const int t = threadIdx.x;
  const int task = blockIdx.x;  // b*21 + c
  const int b = task / NCLS, c = task - b * NCLS;
  float* ob = out + (size_t)task * TOPK * 5;

  if (c == 0) {  // background class: all-zero rows
    float4 z = make_float4(0.f, 0.f, 0.f, 0.f);
    for (int i = t; i < TOPK * 5 / 4; i += NTH) ((float4*)ob)[i] = z;
    return;
  }

  __shared__ alignas(16) int s_hist[4096];           // 16 KB; aliased by s_sup
  __shared__ alignas(16) u64 s_cand[CAND_CAP];       // 8 KB; aliased by s_S / s_rows
  __shared__ u64 s_sel[TOPK];
  __shared__ float4 s_box[256];
  __shared__ float s_area[256];
  __shared__ float s_score[256];
  __shared__ u64 s_alive[4];
  __shared__ short s_kept[TOPK];
  __shared__ int s_wt[8];
  __shared__ int s_res[3];
  __shared__ int s_cnt[3];
  __shared__ int s_m;
  u64* s_sup = (u64*)s_hist;     // 200*4 u64 = 6.4 KB, used after selection
  int* s_S = (int*)s_cand;       // 512 ints, used only during selection
  float* s_rows = (float*)s_cand;  // 1000 floats, epilogue staging

  if (t == 0) { s_cnt[0] = 0; s_cnt[1] = 0; s_cnt[2] = 0; s_m = 0; }
  for (int i = t; i < 4096; i += NTH) s_hist[i] = 0;

  // ---- load this (b,c)'s 8732 normalized keys into registers (20/thread) ----
  uint32_t kv[NCH * 4];
  if (USE_WS) {
    const uint4* kp = (const uint4*)(keys + (size_t)(b * 20 + (c - 1)) * P_BOX);
#pragma unroll
    for (int ch = 0; ch < 4; ++ch) {
      uint4 v = kp[ch * 512 + t];
      kv[ch * 4 + 0] = v.x; kv[ch * 4 + 1] = v.y;
      kv[ch * 4 + 2] = v.z; kv[ch * 4 + 3] = v.w;
    }
    if (t < 135) {
      uint4 v = kp[2048 + t];
      kv[16] = v.x; kv[17] = v.y; kv[18] = v.z; kv[19] = v.w;
    } else {
      kv[16] = LIM; kv[17] = LIM; kv[18] = LIM; kv[19] = LIM;
    }
  } else {
    for (int ch = 0; ch < NCH; ++ch) {
      int p0 = ch * 2048 + 4 * t;
#pragma unroll
      for (int e = 0; e < 4; ++e) {
        int p = p0 + e;
        uint32_t k = LIM;
        if (p < P_BOX) {
          const float* cf = conf + (size_t)(b * P_BOX + p) * NCLS;
          float x[NCLS];
          float mx = -1e30f;
#pragma unroll
          for (int i = 0; i < NCLS; ++i) {
            float v = fminf(fmaxf(cf[i], -100.0f), 100.0f);
            x[i] = v;
            mx = fmaxf(mx, v);
          }
          float ssum = 0.0f, ec = 0.0f;
#pragma unroll
          for (int i = 0; i < NCLS; ++i) {
            float ex = expf(x[i] - mx);
            ssum += ex;
            if (i == c) ec = ex;
          }
          float sc = ec / ssum;
          float4 bx = decode_box(((const float4*)priors)[p],
                                 ((const float4*)loc)[(size_t)b * P_BOX + p]);
          bool valid = (sc > 0.01f) && (bx.z > bx.x + 1e-6f) && (bx.w > bx.y + 1e-6f);
          k = score_key(valid ? sc : -1.0f) - NORM;
        }
        kv[ch * 4 + e] = k;
      }
    }
  }
  __syncthreads();

  // ---- pass 1: 4096-bucket histogram of key bits [25:14] ----
#pragma unroll
  for (int j = 0; j < NCH * 4; ++j)
    if (kv[j] < LIM) atomicAdd(&s_hist[kv[j] >> 14], 1);
  __syncthreads();
  int3 r1 = select_bucket(s_hist, s_S, s_wt, s_res, TOPK, t);
  uint32_t Tp = (uint32_t)r1.x << 14;
  int M = r1.y;
  bool ex = false;
  uint32_t Tex = 0, I = 0;

  if (M > CAND_CAP) {  // rare: refine within bucket (width-4 sub-buckets)
    uint32_t B1 = (uint32_t)r1.x;
    int above1 = r1.z;
    __syncthreads();
    for (int i = t; i < 4096; i += NTH) s_hist[i] = 0;
    __syncthreads();
#pragma unroll
    for (int j = 0; j < NCH * 4; ++j)
      if (kv[j] < LIM && (kv[j] >> 14) == B1)
        atomicAdd(&s_hist[(kv[j] >> 2) & 0xFFF], 1);
    __syncthreads();
    int3 r2 = select_bucket(s_hist, s_S, s_wt, s_res, TOPK - above1, t);
    Tp = (B1 << 14) + ((uint32_t)r2.x << 2);
    M = above1 + r2.y;
    if (M > CAND_CAP) {  // pathological ties: exact key + index refinement
      int it = 0;
      uint32_t lo = Tp, hi = LIM;  // f(lo)=M>=200, f(LIM)=0
      while (hi - lo > 1) {
        uint32_t mid = lo + ((hi - lo) >> 1);
        int cnt = block_count(cnt_ge(kv, mid), t, s_cnt, it);
        if (cnt >= TOPK) lo = mid; else hi = mid;
      }
      Tex = lo;
      int G = block_count(cnt_ge(kv, Tex + 1), t, s_cnt, it);
      int R = TOPK - G;  // >= 1
      uint32_t lo2 = 1, hi2 = P_BOX + 1;
      while (hi2 - lo2 > 1) {
        uint32_t mid = lo2 + ((hi2 - lo2) >> 1);
        int cnt = block_count(cnt_eq_idx(kv, t, Tex, mid), t, s_cnt, it);
        if (cnt >= R) lo2 = mid; else hi2 = mid;
      }
      I = lo2;
      ex = true;  // M becomes exactly 200 at gather
    }
  }
  __syncthreads();  // s_S (alias s_cand) dead; safe to gather

  // ---- gather candidates (packed key|P-p for exact total order) ----
#pragma unroll
  for (int ch = 0; ch < NCH; ++ch) {
#pragma unroll
    for (int e = 0; e < 4; ++e) {
      uint32_t k = kv[ch * 4 + e];
      if (k < LIM) {
        int p = ch * 2048 + 4 * t + e;
        bool take = ex ? (k > Tex || (k == Tex && (uint32_t)(P_BOX - p) >= I))
                       : (k >= Tp);
        if (take) {
          int ix = atomicAdd(&s_m, 1);
          if (ix < CAND_CAP) s_cand[ix] = ((u64)k << 32) | (uint32_t)(P_BOX - p);
        }
      }
    }
  }
  __syncthreads();
  M = min(s_m, CAND_CAP);
  int nsel = min(M, TOPK);

  // ---- rank (exact order; ties by smaller p) and scatter sorted ----
  for (int ci = t; ci < M; ci += NTH) {
    u64 mine = s_cand[ci];
    int r = 0;
    for (int j = 0; j < M; ++j) r += (s_cand[j] > mine) ? 1 : 0;  // LDS broadcast
    if (r < TOPK) s_sel[r] = mine;
  }
  __syncthreads();

  // ---- decode selected boxes; zero-init suppression masks ----
  if (t < 256) {
    if (t < nsel) {
      u64 w = s_sel[t];
      uint32_t k = (uint32_t)(w >> 32);
      int p = P_BOX - (int)(uint32_t)(w & 0xFFFFFFFFull);
      float4 bx = decode_box(((const float4*)priors)[p],
                             ((const float4*)loc)[(size_t)b * P_BOX + p]);
      s_box[t] = bx;
      s_area[t] = (bx.z - bx.x) * (bx.w - bx.y);
      s_score[t] = key_score(k + NORM);
    } else {
      s_box[t] = make_float4(0.f, 0.f, 0.f, 0.f);
      s_area[t] = 0.f;
      s_score[t] = 0.f;
    }
  }
  for (int i = t; i < TOPK * 4; i += NTH) s_sup[i] = 0ull;
  __syncthreads();

  // ---- suppression bitmasks via ballot (8 waves, row-strided) ----
  {
    int wv = t >> 6, l = t & 63;
    float4 bj[4];
    float aj[4];
#pragma unroll
    for (int cc = 0; cc < 4; ++cc) {
      bj[cc] = s_box[cc * 64 + l];
      aj[cc] = s_area[cc * 64 + l];
    }
    for (int i = wv; i < nsel; i += 8) {
      float4 bi = s_box[i];
      float ai = s_area[i];
      int c0 = i >> 6;
      for (int cc = c0; cc < 4; ++cc) {
        int j = cc * 64 + l;
        float lx = fmaxf(bi.x, bj[cc].x), ly = fmaxf(bi.y, bj[cc].y);
        float rx = fminf(bi.z, bj[cc].z), ry = fminf(bi.w, bj[cc].w);
        float iw = fmaxf(rx - lx, 0.0f), ih = fmaxf(ry - ly, 0.0f);
        float inter = iw * ih;
        float uni = ai + aj[cc] - inter;
        float iou = inter / fmaxf(uni, 1e-12f);
        bool sup = (j > i) && (j < nsel) && (iou > 0.45f);
        u64 m = __ballot(sup);
        if (l == 0) s_sup[i * 4 + cc] = m;
      }
    }
  }
  __syncthreads();

  // ---- serial greedy walk, software-pipelined row prefetch ----
  if (t == 0) {
    u64 aw0, aw1, aw2, aw3;
    {
      int r0 = nsel, r1 = nsel - 64, r2 = nsel - 128, r3 = nsel - 192;
      aw0 = r0 >= 64 ? ~0ull : (r0 <= 0 ? 0ull : ((1ull << r0) - 1));
      aw1 = r1 >= 64 ? ~0ull : (r1 <= 0 ? 0ull : ((1ull << r1) - 1));
      aw2 = r2 >= 64 ? ~0ull : (r2 <= 0 ? 0ull : ((1ull << r2) - 1));
      aw3 = r3 >= 64 ? ~0ull : (r3 <= 0 ? 0ull : ((1ull << r3) - 1));
    }
    u64 p0 = s_sup[0], p1 = s_sup[1], p2 = s_sup[2], p3 = s_sup[3];
    for (int i = 0; i < nsel; ++i) {
      u64 c0 = p0, c1 = p1, c2 = p2, c3 = p3;
      int j = i + 1;
      if (j < nsel) {  // prefetch next row before the dependent ANDs
        p0 = s_sup[j * 4 + 0]; p1 = s_sup[j * 4 + 1];
        p2 = s_sup[j * 4 + 2]; p3 = s_sup[j * 4 + 3];
      }
      int w = i >> 6;
      u64 cur = (w == 0) ? aw0 : (w == 1) ? aw1 : (w == 2) ? aw2 : aw3;
      if ((cur >> (i & 63)) & 1ull) {
        aw0 &= ~c0; aw1 &= ~c1; aw2 &= ~c2; aw3 &= ~c3;
      }
    }
    s_alive[0] = aw0; s_alive[1] = aw1; s_alive[2] = aw2; s_alive[3] = aw3;
  }
  __syncthreads();

  // ---- compact kept to front via popcount ranks ----
  u64 w0 = s_alive[0], w1 = s_alive[1], w2 = s_alive[2], w3 = s_alive[3];
  int pc0 = __popcll(w0), pc01 = pc0 + __popcll(w1), pc012 = pc01 + __popcll(w2);
  int nk = pc012 + __popcll(w3);
  if (t < nsel) {
    int word = t >> 6, bit = t & 63;
    u64 wt = (word == 0) ? w0 : (word == 1) ? w1 : (word == 2) ? w2 : w3;
    if ((wt >> bit) & 1ull) {
      int base = (word == 0) ? 0 : (word == 1) ? pc0 : (word == 2) ? pc01 : pc012;
      int r = base + __popcll(wt & ((1ull << bit) - 1ull));
      s_kept[r] = (short)t;
    }
  }
  __syncthreads();

  // ---- stage rows in LDS, then coalesced float4 store ----
  if (t < TOPK) {
    float r0 = 0.f, r1 = 0.f, r2 = 0.f, r3 = 0.f, r4 = 0.f;
    if (t < nk) {
      int j = s_kept[t];
      r0 = s_score[j];
      float4 bx = s_box[j];
      r1 = bx.x; r2 = bx.y; r3 = bx.z; r4 = bx.w;
    }
    s_rows[t * 5 + 0] = r0; s_rows[t * 5 + 1] = r1; s_rows[t * 5 + 2] = r2;
    s_rows[t * 5 + 3] = r3; s_rows[t * 5 + 4] = r4;
  }
  __syncthreads();
  for (int i = t; i < TOPK * 5 / 4; i += NTH)
    ((float4*)ob)[i] = ((float4*)s_rows)[i];
}

extern "C" void kernel_launch(void* const* d_in, const int* in_sizes, int n_in,
                              void* d_out, int out_size, void* d_ws, size_t ws_size,
                              hipStream_t stream) {
  (void)in_sizes;
  (void)n_in;
  (void)out_size;
  const float* loc = (const float*)d_in[0];     // [B,P,4]
  const float* conf = (const float*)d_in[1];    // [B,P,21]
  const float* priors = (const float*)d_in[2];  // [P,4]
  float* out = (float*)d_out;                   // [B,21,200,5]

  size_t keys_bytes = (size_t)BATCH * 20 * P_BOX * sizeof(uint32_t);  // 22.35 MB
  if (ws_size >= keys_bytes) {
    uint32_t* keys = (uint32_t*)d_ws;
    int nprep = (NBOX_TOTAL + 255) / 256;
    prep_kernel<<<nprep, 256, 0, stream>>>(loc, conf, priors, keys);
    nms_kernel<true><<<BATCH * NCLS, NTH, 0, stream>>>(loc, conf, priors, keys, out);
  } else {
    nms_kernel<false><<<BATCH * NCLS, NTH, 0, stream>>>(loc, conf, priors, nullptr, out);
  }
}